// Round 16
// baseline (317.165 us; speedup 1.0000x reference)
//
#include <hip/hip_runtime.h>
#include <stdint.h>

typedef unsigned short ushort_t;
typedef _Float16 f16;
typedef __attribute__((ext_vector_type(8))) _Float16 half8;
typedef __attribute__((ext_vector_type(4))) _Float16 half4;
typedef __attribute__((ext_vector_type(4))) float float4v;

#define AS1 __attribute__((address_space(1)))
#define AS3 __attribute__((address_space(3)))

static __device__ __forceinline__ void gload16(const void* g, void* l) {
    __builtin_amdgcn_global_load_lds((const AS1 unsigned int*)g,
                                     (AS3 unsigned int*)l, 16, 0, 0);
}

static __device__ __forceinline__ void barrier_nodrain() {
    __builtin_amdgcn_sched_barrier(0);
    __builtin_amdgcn_s_barrier();
    __builtin_amdgcn_sched_barrier(0);
}

// vmcnt(N) with lgkm/exp skipped -- builtin requires literal constant.
#define VMCNT(N) __builtin_amdgcn_s_waitcnt(0x0F70 | (N))

// =====================================================================
// 256x256 8-phase GEMM (T3+T4+T5), f16 MFMA, A*B^T (+bias).
// Use ONLY for grids divisible by 256 at 1 block/CU (128 KiB LDS).
// scores: 8x8x4 = 256 exactly. Harness-verified OUT=1,4 (R8/R9).
// =====================================================================
#define PH_LDA(cb, ks, mlo)                                                   \
    _Pragma("unroll")                                                         \
    for (int m_ = 0; m_ < 4; ++m_)                                            \
        aR[m_] = *(const half8*)(smem + (cb) + (ks)*8192 + aoff + ((mlo)+m_)*512);

#define PH_LDB(cb, ks)                                                        \
    _Pragma("unroll")                                                         \
    for (int n_ = 0; n_ < 4; ++n_)                                            \
        bR[n_] = *(const half8*)(smem + (cb) + (ks)*8192 + boff + n_*512);

#define PH_MM(mlo)                                                            \
    __builtin_amdgcn_s_setprio(1);                                            \
    _Pragma("unroll")                                                         \
    for (int m_ = 0; m_ < 4; ++m_) {                                          \
        _Pragma("unroll")                                                     \
        for (int n_ = 0; n_ < 4; ++n_)                                        \
            acc[(mlo)+m_][n_] = __builtin_amdgcn_mfma_f32_16x16x32_f16(       \
                aR[m_], bR[n_], acc[(mlo)+m_][n_], 0, 0, 0);                  \
    }                                                                         \
    __builtin_amdgcn_s_setprio(0);

template<int OUT, bool BIAS>
__global__ __launch_bounds__(512, 2)
void gemm8_k(const f16* __restrict__ A, const f16* __restrict__ B,
             const float* __restrict__ bias,
             float* __restrict__ Cf, f16* __restrict__ Ch, f16* __restrict__ Vt,
             int K, int lda, int ldb, int ldc,
             long zsA, long zsB, long zsC)
{
    extern __shared__ f16 smem[];
    const long zb = blockIdx.z;
    A += zb * zsA; B += zb * zsB;
    const int tid = threadIdx.x;
    const int bm = blockIdx.x * 256;
    const int bn = blockIdx.y * 256;

    const int srow = tid >> 2;
    const int sk   = (((tid & 3) ^ ((tid >> 3) & 3)) * 8);
    const f16* gA = A + (long)(bm + srow) * lda + sk;
    const f16* gB = B + (long)(bn + srow) * ldb + sk;
    const long hA = (long)128 * lda;
    const long hB = (long)128 * ldb;

    const int lane = tid & 63;
    const int wv = tid >> 6;
    const int wm = wv >> 2;
    const int wn = wv & 3;
    const int lm = lane & 15;
    const int q  = lane >> 4;
    const int qs8  = (q ^ ((lm >> 1) & 3)) * 8;
    const int aoff = (wm * 128 + lm) * 32 + qs8;
    const int boff = 16384 + (wn * 64 + lm) * 32 + qs8;

    float4v acc[8][4];
    #pragma unroll
    for (int i = 0; i < 8; ++i)
        #pragma unroll
        for (int j = 0; j < 4; ++j)
            #pragma unroll
            for (int r = 0; r < 4; ++r) acc[i][j][r] = 0.f;

    auto stA = [&](int tt, int ks) {
        f16* d = smem + (tt & 1) * 32768 + ks * 8192 + tid * 8;
        const f16* g = gA + (long)tt * 64 + ks * 32;
        gload16(g,      d);
        gload16(g + hA, d + 4096);
    };
    auto stB = [&](int tt, int ks) {
        f16* d = smem + (tt & 1) * 32768 + 16384 + ks * 8192 + tid * 8;
        const f16* g = gB + (long)tt * 64 + ks * 32;
        gload16(g,      d);
        gload16(g + hB, d + 4096);
    };

    half8 aR[4], bR[4];
    const int T = K >> 6;

    stA(0, 0); stB(0, 0); stA(0, 1); stB(0, 1);
    if (T > 1) { stA(1, 0); stB(1, 0); VMCNT(8); }
    else       { VMCNT(4); }
    barrier_nodrain();

    for (int t = 0; t < T; ++t) {
        const int cb = (t & 1) * 32768;
        PH_LDA(cb, 0, 0)
        PH_LDB(cb, 0)
        if (t + 1 < T) stA(t + 1, 1);
        barrier_nodrain();
        PH_MM(0)
        barrier_nodrain();
        PH_LDA(cb, 0, 4)
        if (t + 1 < T) { stB(t + 1, 1); VMCNT(8); }
        else           { VMCNT(0); }
        barrier_nodrain();
        PH_MM(4)
        barrier_nodrain();
        PH_LDA(cb, 1, 0)
        PH_LDB(cb, 1)
        if (t + 2 < T) stA(t + 2, 0);
        barrier_nodrain();
        PH_MM(0)
        barrier_nodrain();
        PH_LDA(cb, 1, 4)
        if (t + 2 < T) { stB(t + 2, 0); VMCNT(8); }
        else if (t + 1 < T) { VMCNT(4); }
        barrier_nodrain();
        PH_MM(4)
        barrier_nodrain();
    }

    #pragma unroll
    for (int mf = 0; mf < 8; ++mf) {
        const int rowb = bm + wm * 128 + mf * 16 + q * 4;
        #pragma unroll
        for (int nf = 0; nf < 4; ++nf) {
            const int col = bn + wn * 64 + nf * 16 + lm;
            const float bv_ = BIAS ? bias[col] : 0.f;
            if (OUT == 4 && col >= 2048) {
                half4 pk;
                #pragma unroll
                for (int r = 0; r < 4; ++r) pk[r] = (f16)(acc[mf][nf][r] + bv_);
                *(half4*)(Vt + ((long)(rowb >> 11) * 1024 + (col - 2048)) * 2048 + (rowb & 2047)) = pk;
            } else {
                #pragma unroll
                for (int r = 0; r < 4; ++r) {
                    const float val = acc[mf][nf][r] + bv_;
                    const int row = rowb + r;
                    if (OUT == 0)      Cf[zb * zsC + (long)row * ldc + col] = val;
                    else if (OUT == 1) Ch[zb * zsC + (long)row * ldc + col] = (f16)val;
                    else               Ch[(long)row * ldc + col] = (f16)val;
                }
            }
        }
    }
}

// ---------------------------------------------------------------------
// R10: gemm_k2 -- 2-buf, prefetch distance 1, 32 KiB LDS -> 5 blocks/CU
// (20 waves/CU, launch_bounds(256,5); VGPR 52 so no spill pressure).
// Structure == prior-session-verified 253.1 µs kernel's schedule
// (2-buf, stage-before-vmcnt, two barriers/iter) at IM=4 geometry.
// Race proof: stage(s+1) overwrites buf[(s+1)&1], last read by
// compute(s-1), fenced by iter s-1's closing barrier (passed by all
// waves before any wave issues stage(s+1)). vmcnt(NLD) retires all of
// stage(s) (only stage(s+1)'s NLD loads newer); barrier publishes all
// waves' slabs. Swizzle unchanged (R6: conflicts 6.29M -> 0).
// ---------------------------------------------------------------------
template<int IM, int OUT, bool BIAS>
__global__ __launch_bounds__(256, 5)
void gemm_k2(const f16* __restrict__ A, const f16* __restrict__ B,
             const float* __restrict__ bias,
             float* __restrict__ Cf, f16* __restrict__ Ch, f16* __restrict__ Vt,
             int K, int lda, int ldb, int ldc,
             long zsA, long zsB, long zsC)
{
    constexpr int R    = IM * 32;        // 128
    constexpr int AH   = R * 32;         // halves per A stage buffer
    constexpr int NLD  = R / 64 + 2;     // 4
    extern __shared__ f16 smem[];
    // layout: [A0 | A1 | B0 | B1]  (2 buffers)

    const long zb = blockIdx.z;
    A += zb * zsA; B += zb * zsB;

    const int t  = threadIdx.x;
    const int bm = blockIdx.x * R;
    const int bn = blockIdx.y * 128;

    const int  srow = t >> 2;
    const int  skg  = (((t & 3) ^ ((srow >> 1) & 3)) * 8);
    const f16* gA = A + (long)(bm + srow) * lda + skg;
    const f16* gB = B + (long)(bn + srow) * ldb + skg;
    const long rstepA = (long)64 * lda;
    const long rstepB = (long)64 * ldb;

    const int lane = t & 63;
    const int wv   = t >> 6;
    const int wm   = (wv & 1) * (IM * 16);
    const int wn   = (wv >> 1) * 64;
    const int lm   = lane & 15;
    const int q    = lane >> 4;
    const int qs   = (q ^ ((lm >> 1) & 3)) * 8;

    float4v acc[IM][4];
    #pragma unroll
    for (int i = 0; i < IM; ++i)
        #pragma unroll
        for (int j = 0; j < 4; ++j)
            #pragma unroll
            for (int r = 0; r < 4; ++r) acc[i][j][r] = 0.f;

    auto stage = [&](int s) {
        const int kk  = s << 5;
        const int buf = s & 1;
        f16* dA = smem + buf * AH;
        f16* dB = smem + 2 * AH + buf * 4096;
        #pragma unroll
        for (int r = 0; r < R / 64; ++r)
            gload16(gA + kk + r * rstepA, dA + r * 2048 + t * 8);
        #pragma unroll
        for (int r = 0; r < 2; ++r)
            gload16(gB + kk + r * rstepB, dB + r * 2048 + t * 8);
    };

    const int nstage = K >> 5;
    stage(0);
    for (int s = 0; s < nstage; ++s) {
        if (s + 1 < nstage) {
            stage(s + 1);
            VMCNT(NLD);          // retire stage(s); stage(s+1) in flight
        } else {
            VMCNT(0);
        }
        barrier_nodrain();       // publish stage(s) across waves

        const int buf = s & 1;
        const f16* sA = smem + buf * AH;
        const f16* sB = smem + 2 * AH + buf * 4096;
        half8 a[IM], b[4];
        #pragma unroll
        for (int i = 0; i < IM; ++i)
            a[i] = *(const half8*)(sA + (wm + i * 16 + lm) * 32 + qs);
        #pragma unroll
        for (int j = 0; j < 4; ++j)
            b[j] = *(const half8*)(sB + (wn + j * 16 + lm) * 32 + qs);
        #pragma unroll
        for (int i = 0; i < IM; ++i)
            #pragma unroll
            for (int j = 0; j < 4; ++j)
                acc[i][j] = __builtin_amdgcn_mfma_f32_16x16x32_f16(a[i], b[j], acc[i][j], 0, 0, 0);

        barrier_nodrain();       // fence: next stage overwrite vs readers
    }

    #pragma unroll
    for (int i = 0; i < IM; ++i) {
        const int rowb = bm + wm + i * 16 + q * 4;
        #pragma unroll
        for (int j = 0; j < 4; ++j) {
            const int col = bn + wn + j * 16 + lm;
            const float bv_ = BIAS ? bias[col] : 0.f;
            if (OUT == 4 && col >= 2048) {
                half4 pk;
                #pragma unroll
                for (int r = 0; r < 4; ++r) pk[r] = (f16)(acc[i][j][r] + bv_);
                *(half4*)(Vt + ((long)(rowb >> 11) * 1024 + (col - 2048)) * 2048 + (rowb & 2047)) = pk;
            } else {
                #pragma unroll
                for (int r = 0; r < 4; ++r) {
                    const float val = acc[i][j][r] + bv_;
                    const int row = rowb + r;
                    if (OUT == 0)      Cf[zb * zsC + (long)row * ldc + col] = val;
                    else if (OUT == 1) Ch[zb * zsC + (long)row * ldc + col] = (f16)val;
                    else               Ch[(long)row * ldc + col] = (f16)val;
                }
            }
        }
    }
}

// ---------------------------------------------------------------------
// fused preprocessing, one dispatch (unchanged)
// ---------------------------------------------------------------------
__global__ __launch_bounds__(256)
void preproc_k(const float* __restrict__ x,
               const float* __restrict__ Wq, const float* __restrict__ Wk,
               const float* __restrict__ Wv,
               const float* __restrict__ bq, const float* __restrict__ bk,
               const float* __restrict__ bv,
               f16* __restrict__ xh, f16* __restrict__ WT, float* __restrict__ bqkv)
{
    __shared__ float tile[64][65];
    const int bx = blockIdx.x;
    const int t  = threadIdx.x;

    if (bx < 8192) {
        const long i = ((long)bx * 256 + t) * 4;
        const float4v v = *(const float4v*)(x + i);
        half4 h;
        #pragma unroll
        for (int j = 0; j < 4; ++j) h[j] = (f16)v[j];
        *(half4*)(xh + i) = h;
    } else if (bx < 8960) {
        const int f = bx - 8192;
        const int z = f >> 8;
        const int rem = f & 255;
        const int n0 = (rem & 15) * 64;
        const int k0 = (rem >> 4) * 64;
        const float* W = (z == 0) ? Wq : (z == 1) ? Wk : Wv;
        f16* T = WT + (long)z * 1048576;
        #pragma unroll
        for (int i = 0; i < 4; ++i) {
            const int r = (t >> 4) + i * 16;
            const int c = (t & 15) * 4;
            const float4v v = *(const float4v*)(W + (long)(k0 + r) * 1024 + n0 + c);
            tile[r][c + 0] = v[0]; tile[r][c + 1] = v[1];
            tile[r][c + 2] = v[2]; tile[r][c + 3] = v[3];
        }
        __syncthreads();
        #pragma unroll
        for (int i = 0; i < 4; ++i) {
            const int nr = (t >> 4) + i * 16;
            const int c  = (t & 15) * 4;
            half4 h;
            #pragma unroll
            for (int j = 0; j < 4; ++j) h[j] = (f16)tile[c + j][nr];
            *(half4*)(T + (long)(n0 + nr) * 1024 + k0 + c) = h;
        }
    } else {
        const int i = (bx - 8960) * 256 + t;
        bqkv[i] = (i < 1024) ? bq[i] : (i < 2048) ? bk[i - 1024] : bv[i - 2048];
    }
}

// ---- row softmax, in place: f16 [rows, 2048] (unchanged) ----
__global__ __launch_bounds__(256)
void softmax_k(f16* __restrict__ Sc)
{
    const int t = threadIdx.x;
    const long row = blockIdx.x;
    half8* p = (half8*)(Sc + row * 2048);
    const half8 hv = p[t];
    float xv[8];
    #pragma unroll
    for (int j = 0; j < 8; ++j) xv[j] = (float)hv[j];

    float m = -1e30f;
    #pragma unroll
    for (int j = 0; j < 8; ++j) m = fmaxf(m, xv[j]);
    #pragma unroll
    for (int off = 32; off; off >>= 1) m = fmaxf(m, __shfl_xor(m, off, 64));
    __shared__ float r1[4], r2[4];
    if ((t & 63) == 0) r1[t >> 6] = m;
    __syncthreads();
    m = fmaxf(fmaxf(r1[0], r1[1]), fmaxf(r1[2], r1[3]));

    float s = 0.f;
    #pragma unroll
    for (int j = 0; j < 8; ++j) { xv[j] = __expf(xv[j] - m); s += xv[j]; }
    #pragma unroll
    for (int off = 32; off; off >>= 1) s += __shfl_xor(s, off, 64);
    if ((t & 63) == 0) r2[t >> 6] = s;
    __syncthreads();
    s = r2[0] + r2[1] + r2[2] + r2[3];
    const float inv = 1.f / s;

    half8 o;
    #pragma unroll
    for (int j = 0; j < 8; ++j) o[j] = (f16)(xv[j] * inv);
    p[t] = o;
}

// ---------------------------------------------------------------------
extern "C" void kernel_launch(void* const* d_in, const int* in_sizes, int n_in,
                              void* d_out, int out_size, void* d_ws, size_t ws_size,
                              hipStream_t stream)
{
    const float* x  = (const float*)d_in[0];
    const float* Wq = (const float*)d_in[1];
    const float* bq = (const float*)d_in[2];
    const float* Wk = (const float*)d_in[3];
    const float* bk = (const float*)d_in[4];
    const float* Wv = (const float*)d_in[5];
    const float* bv = (const float*)d_in[6];
    float* out = (float*)d_out;

    char* ws = (char*)d_ws;
    const long MiB = 1024 * 1024;
    f16*   xh   = (f16*)  (ws + 0);          // 16 MiB [8192,1024]
    f16*   WT   = (f16*)  (ws + 16 * MiB);   //  6 MiB [3072,1024]
    float* bqkv = (float*)(ws + 22 * MiB);   // 12 KiB
    f16*   scores = (f16*) (ws + 0);         // 32 MiB [4][2048][2048]
    f16*   qk     = (f16*) (ws + 64 * MiB);  // 32 MiB [8192,2048]
    f16*   vT     = (f16*) (ws + 96 * MiB);  // 16 MiB [4][1024][2048]

    // 1) fused preprocessing
    preproc_k<<<8972, 256, 0, stream>>>(x, Wq, Wk, Wv, bq, bk, bv, xh, WT, bqkv);

    // 2) fused QKV projection: 128^2 2-buf @ 5 blocks/CU (R10 TLP probe)
    gemm_k2<4, 4, true><<<dim3(64, 24, 1), 256, 32768, stream>>>(
        xh, WT, bqkv, nullptr, qk, vT,
        1024, 1024, 1024, 2048, 0, 0, 0);

    // 3) attention: scores via 256^2 8-phase (held constant for attribution)
    const long SS = (long)2048 * 2048;
    gemm8_k<1, false><<<dim3(8, 8, 4), 512, 131072, stream>>>(
        qk, qk + 1024, nullptr, nullptr, scores, nullptr,
        1024, 2048, 2048, 2048, SS, SS, SS);
    softmax_k<<<8192, 256, 0, stream>>>(scores);
    gemm_k2<4, 0, false><<<dim3(16, 8, 4), 256, 32768, stream>>>(
        scores, vT, nullptr, out, nullptr, nullptr,
        2048, 2048, 2048, 1024, SS, (long)1024 * 2048, (long)2048 * 1024);
}

// Round 18
// 257.147 us; speedup vs baseline: 1.2334x; 1.2334x over previous
//
#include <hip/hip_runtime.h>
#include <stdint.h>

typedef unsigned short ushort_t;
typedef _Float16 f16;
typedef __attribute__((ext_vector_type(8))) _Float16 half8;
typedef __attribute__((ext_vector_type(4))) _Float16 half4;
typedef __attribute__((ext_vector_type(4))) float float4v;

#define AS1 __attribute__((address_space(1)))
#define AS3 __attribute__((address_space(3)))

static __device__ __forceinline__ void gload16(const void* g, void* l) {
    __builtin_amdgcn_global_load_lds((const AS1 unsigned int*)g,
                                     (AS3 unsigned int*)l, 16, 0, 0);
}

static __device__ __forceinline__ void barrier_nodrain() {
    __builtin_amdgcn_sched_barrier(0);
    __builtin_amdgcn_s_barrier();
    __builtin_amdgcn_sched_barrier(0);
}

// vmcnt(N) with lgkm/exp skipped -- builtin requires literal constant.
#define VMCNT(N) __builtin_amdgcn_s_waitcnt(0x0F70 | (N))

// =====================================================================
// Session-best configuration (R9, verified 260.6 us PASS):
//   preproc -> gemm_k<4,4> QKV (128^2 3-buf, 1536 blocks)
//           -> gemm8_k<1> scores (256^2 8-phase, 256 blocks = 1 round)
//           -> softmax -> gemm_k<4,0> PV.
// Structure-space search complete; both directions from this optimum
// measured and worse (R8 packing loss, R16 depth loss). Routing rule:
// gemm8_k only for grids divisible by 256; gemm_k 3-buf otherwise.
// =====================================================================

// ---------------------------------------------------------------------
// 256x256 8-phase GEMM (T3+T4+T5), f16 MFMA, A*B^T (+bias).
// scores: 8x8x4 = 256 blocks = exactly one round. Verified OUT=1,4.
// ---------------------------------------------------------------------
#define PH_LDA(cb, ks, mlo)                                                   \
    _Pragma("unroll")                                                         \
    for (int m_ = 0; m_ < 4; ++m_)                                            \
        aR[m_] = *(const half8*)(smem + (cb) + (ks)*8192 + aoff + ((mlo)+m_)*512);

#define PH_LDB(cb, ks)                                                        \
    _Pragma("unroll")                                                         \
    for (int n_ = 0; n_ < 4; ++n_)                                            \
        bR[n_] = *(const half8*)(smem + (cb) + (ks)*8192 + boff + n_*512);

#define PH_MM(mlo)                                                            \
    __builtin_amdgcn_s_setprio(1);                                            \
    _Pragma("unroll")                                                         \
    for (int m_ = 0; m_ < 4; ++m_) {                                          \
        _Pragma("unroll")                                                     \
        for (int n_ = 0; n_ < 4; ++n_)                                        \
            acc[(mlo)+m_][n_] = __builtin_amdgcn_mfma_f32_16x16x32_f16(       \
                aR[m_], bR[n_], acc[(mlo)+m_][n_], 0, 0, 0);                  \
    }                                                                         \
    __builtin_amdgcn_s_setprio(0);

template<int OUT, bool BIAS>
__global__ __launch_bounds__(512, 2)
void gemm8_k(const f16* __restrict__ A, const f16* __restrict__ B,
             const float* __restrict__ bias,
             float* __restrict__ Cf, f16* __restrict__ Ch, f16* __restrict__ Vt,
             int K, int lda, int ldb, int ldc,
             long zsA, long zsB, long zsC)
{
    extern __shared__ f16 smem[];
    const long zb = blockIdx.z;
    A += zb * zsA; B += zb * zsB;
    const int tid = threadIdx.x;
    const int bm = blockIdx.x * 256;
    const int bn = blockIdx.y * 256;

    const int srow = tid >> 2;
    const int sk   = (((tid & 3) ^ ((tid >> 3) & 3)) * 8);
    const f16* gA = A + (long)(bm + srow) * lda + sk;
    const f16* gB = B + (long)(bn + srow) * ldb + sk;
    const long hA = (long)128 * lda;
    const long hB = (long)128 * ldb;

    const int lane = tid & 63;
    const int wv = tid >> 6;
    const int wm = wv >> 2;
    const int wn = wv & 3;
    const int lm = lane & 15;
    const int q  = lane >> 4;
    const int qs8  = (q ^ ((lm >> 1) & 3)) * 8;
    const int aoff = (wm * 128 + lm) * 32 + qs8;
    const int boff = 16384 + (wn * 64 + lm) * 32 + qs8;

    float4v acc[8][4];
    #pragma unroll
    for (int i = 0; i < 8; ++i)
        #pragma unroll
        for (int j = 0; j < 4; ++j)
            #pragma unroll
            for (int r = 0; r < 4; ++r) acc[i][j][r] = 0.f;

    auto stA = [&](int tt, int ks) {
        f16* d = smem + (tt & 1) * 32768 + ks * 8192 + tid * 8;
        const f16* g = gA + (long)tt * 64 + ks * 32;
        gload16(g,      d);
        gload16(g + hA, d + 4096);
    };
    auto stB = [&](int tt, int ks) {
        f16* d = smem + (tt & 1) * 32768 + 16384 + ks * 8192 + tid * 8;
        const f16* g = gB + (long)tt * 64 + ks * 32;
        gload16(g,      d);
        gload16(g + hB, d + 4096);
    };

    half8 aR[4], bR[4];
    const int T = K >> 6;

    stA(0, 0); stB(0, 0); stA(0, 1); stB(0, 1);
    if (T > 1) { stA(1, 0); stB(1, 0); VMCNT(8); }
    else       { VMCNT(4); }
    barrier_nodrain();

    for (int t = 0; t < T; ++t) {
        const int cb = (t & 1) * 32768;
        PH_LDA(cb, 0, 0)
        PH_LDB(cb, 0)
        if (t + 1 < T) stA(t + 1, 1);
        barrier_nodrain();
        PH_MM(0)
        barrier_nodrain();
        PH_LDA(cb, 0, 4)
        if (t + 1 < T) { stB(t + 1, 1); VMCNT(8); }
        else           { VMCNT(0); }
        barrier_nodrain();
        PH_MM(4)
        barrier_nodrain();
        PH_LDA(cb, 1, 0)
        PH_LDB(cb, 1)
        if (t + 2 < T) stA(t + 2, 0);
        barrier_nodrain();
        PH_MM(0)
        barrier_nodrain();
        PH_LDA(cb, 1, 4)
        if (t + 2 < T) { stB(t + 2, 0); VMCNT(8); }
        else if (t + 1 < T) { VMCNT(4); }
        barrier_nodrain();
        PH_MM(4)
        barrier_nodrain();
    }

    #pragma unroll
    for (int mf = 0; mf < 8; ++mf) {
        const int rowb = bm + wm * 128 + mf * 16 + q * 4;
        #pragma unroll
        for (int nf = 0; nf < 4; ++nf) {
            const int col = bn + wn * 64 + nf * 16 + lm;
            const float bv_ = BIAS ? bias[col] : 0.f;
            if (OUT == 4 && col >= 2048) {
                half4 pk;
                #pragma unroll
                for (int r = 0; r < 4; ++r) pk[r] = (f16)(acc[mf][nf][r] + bv_);
                *(half4*)(Vt + ((long)(rowb >> 11) * 1024 + (col - 2048)) * 2048 + (rowb & 2047)) = pk;
            } else {
                #pragma unroll
                for (int r = 0; r < 4; ++r) {
                    const float val = acc[mf][nf][r] + bv_;
                    const int row = rowb + r;
                    if (OUT == 0)      Cf[zb * zsC + (long)row * ldc + col] = val;
                    else if (OUT == 1) Ch[zb * zsC + (long)row * ldc + col] = (f16)val;
                    else               Ch[(long)row * ldc + col] = (f16)val;
                }
            }
        }
    }
}

// ---------------------------------------------------------------------
// 128x128 3-buf kernel, prefetch distance 2, ONE barrier/stage,
// both-sides XOR swizzle (R6: conflicts 6.29M -> 0). Verified best for
// QKV (72.9 us, 707 TF) and PV. 48 KiB LDS -> 3 blocks/CU, 12 waves.
// Race proof: stage(s+2) writes buf[(s-1)%3]; its readers finished
// compute(s-1) before barrier(s); stage(s+2) issues after barrier(s).
// vmcnt(NLD) retires stage(s) (issued 2 iters ago, ~free).
// ---------------------------------------------------------------------
template<int IM, int OUT, bool BIAS>
__global__ __launch_bounds__(256, IM == 8 ? 2 : 3)
void gemm_k(const f16* __restrict__ A, const f16* __restrict__ B,
            const float* __restrict__ bias,
            float* __restrict__ Cf, f16* __restrict__ Ch, f16* __restrict__ Vt,
            int K, int lda, int ldb, int ldc,
            long zsA, long zsB, long zsC)
{
    constexpr int R    = IM * 32;
    constexpr int AH   = R * 32;
    constexpr int NLD  = R / 64 + 2;
    extern __shared__ f16 smem[];

    const long zb = blockIdx.z;
    A += zb * zsA; B += zb * zsB;

    const int t  = threadIdx.x;
    const int bm = blockIdx.x * R;
    const int bn = blockIdx.y * 128;

    const int  srow = t >> 2;
    const int  skg  = (((t & 3) ^ ((srow >> 1) & 3)) * 8);
    const f16* gA = A + (long)(bm + srow) * lda + skg;
    const f16* gB = B + (long)(bn + srow) * ldb + skg;
    const long rstepA = (long)64 * lda;
    const long rstepB = (long)64 * ldb;

    const int lane = t & 63;
    const int wv   = t >> 6;
    const int wm   = (wv & 1) * (IM * 16);
    const int wn   = (wv >> 1) * 64;
    const int lm   = lane & 15;
    const int q    = lane >> 4;
    const int qs   = (q ^ ((lm >> 1) & 3)) * 8;

    float4v acc[IM][4];
    #pragma unroll
    for (int i = 0; i < IM; ++i)
        #pragma unroll
        for (int j = 0; j < 4; ++j)
            #pragma unroll
            for (int r = 0; r < 4; ++r) acc[i][j][r] = 0.f;

    auto stage = [&](int s) {
        const int kk  = s << 5;
        const int buf = s % 3;
        f16* dA = smem + buf * AH;
        f16* dB = smem + 3 * AH + buf * 4096;
        #pragma unroll
        for (int r = 0; r < R / 64; ++r)
            gload16(gA + kk + r * rstepA, dA + r * 2048 + t * 8);
        #pragma unroll
        for (int r = 0; r < 2; ++r)
            gload16(gB + kk + r * rstepB, dB + r * 2048 + t * 8);
    };

    const int nstage = K >> 5;
    stage(0);
    stage(1);
    for (int s = 0; s < nstage; ++s) {
        if (s + 1 < nstage) {
            VMCNT(NLD);
        } else {
            VMCNT(0);
        }
        barrier_nodrain();

        if (s + 2 < nstage) {
            stage(s + 2);
            __builtin_amdgcn_sched_barrier(0);
        }

        const int buf = s % 3;
        const f16* sA = smem + buf * AH;
        const f16* sB = smem + 3 * AH + buf * 4096;
        half8 a[IM], b[4];
        #pragma unroll
        for (int i = 0; i < IM; ++i)
            a[i] = *(const half8*)(sA + (wm + i * 16 + lm) * 32 + qs);
        #pragma unroll
        for (int j = 0; j < 4; ++j)
            b[j] = *(const half8*)(sB + (wn + j * 16 + lm) * 32 + qs);
        #pragma unroll
        for (int i = 0; i < IM; ++i)
            #pragma unroll
            for (int j = 0; j < 4; ++j)
                acc[i][j] = __builtin_amdgcn_mfma_f32_16x16x32_f16(a[i], b[j], acc[i][j], 0, 0, 0);
    }

    #pragma unroll
    for (int i = 0; i < IM; ++i) {
        const int rowb = bm + wm + i * 16 + q * 4;
        #pragma unroll
        for (int j = 0; j < 4; ++j) {
            const int col = bn + wn + j * 16 + lm;
            const float bv_ = BIAS ? bias[col] : 0.f;
            if (OUT == 4 && col >= 2048) {
                half4 pk;
                #pragma unroll
                for (int r = 0; r < 4; ++r) pk[r] = (f16)(acc[i][j][r] + bv_);
                *(half4*)(Vt + ((long)(rowb >> 11) * 1024 + (col - 2048)) * 2048 + (rowb & 2047)) = pk;
            } else {
                #pragma unroll
                for (int r = 0; r < 4; ++r) {
                    const float val = acc[i][j][r] + bv_;
                    const int row = rowb + r;
                    if (OUT == 0)      Cf[zb * zsC + (long)row * ldc + col] = val;
                    else if (OUT == 1) Ch[zb * zsC + (long)row * ldc + col] = (f16)val;
                    else               Ch[(long)row * ldc + col] = (f16)val;
                }
            }
        }
    }
}

// ---------------------------------------------------------------------
// fused preprocessing, one dispatch (unchanged)
// ---------------------------------------------------------------------
__global__ __launch_bounds__(256)
void preproc_k(const float* __restrict__ x,
               const float* __restrict__ Wq, const float* __restrict__ Wk,
               const float* __restrict__ Wv,
               const float* __restrict__ bq, const float* __restrict__ bk,
               const float* __restrict__ bv,
               f16* __restrict__ xh, f16* __restrict__ WT, float* __restrict__ bqkv)
{
    __shared__ float tile[64][65];
    const int bx = blockIdx.x;
    const int t  = threadIdx.x;

    if (bx < 8192) {
        const long i = ((long)bx * 256 + t) * 4;
        const float4v v = *(const float4v*)(x + i);
        half4 h;
        #pragma unroll
        for (int j = 0; j < 4; ++j) h[j] = (f16)v[j];
        *(half4*)(xh + i) = h;
    } else if (bx < 8960) {
        const int f = bx - 8192;
        const int z = f >> 8;
        const int rem = f & 255;
        const int n0 = (rem & 15) * 64;
        const int k0 = (rem >> 4) * 64;
        const float* W = (z == 0) ? Wq : (z == 1) ? Wk : Wv;
        f16* T = WT + (long)z * 1048576;
        #pragma unroll
        for (int i = 0; i < 4; ++i) {
            const int r = (t >> 4) + i * 16;
            const int c = (t & 15) * 4;
            const float4v v = *(const float4v*)(W + (long)(k0 + r) * 1024 + n0 + c);
            tile[r][c + 0] = v[0]; tile[r][c + 1] = v[1];
            tile[r][c + 2] = v[2]; tile[r][c + 3] = v[3];
        }
        __syncthreads();
        #pragma unroll
        for (int i = 0; i < 4; ++i) {
            const int nr = (t >> 4) + i * 16;
            const int c  = (t & 15) * 4;
            half4 h;
            #pragma unroll
            for (int j = 0; j < 4; ++j) h[j] = (f16)tile[c + j][nr];
            *(half4*)(T + (long)(n0 + nr) * 1024 + k0 + c) = h;
        }
    } else {
        const int i = (bx - 8960) * 256 + t;
        bqkv[i] = (i < 1024) ? bq[i] : (i < 2048) ? bk[i - 1024] : bv[i - 2048];
    }
}

// ---- row softmax, in place: f16 [rows, 2048] (unchanged) ----
__global__ __launch_bounds__(256)
void softmax_k(f16* __restrict__ Sc)
{
    const int t = threadIdx.x;
    const long row = blockIdx.x;
    half8* p = (half8*)(Sc + row * 2048);
    const half8 hv = p[t];
    float xv[8];
    #pragma unroll
    for (int j = 0; j < 8; ++j) xv[j] = (float)hv[j];

    float m = -1e30f;
    #pragma unroll
    for (int j = 0; j < 8; ++j) m = fmaxf(m, xv[j]);
    #pragma unroll
    for (int off = 32; off; off >>= 1) m = fmaxf(m, __shfl_xor(m, off, 64));
    __shared__ float r1[4], r2[4];
    if ((t & 63) == 0) r1[t >> 6] = m;
    __syncthreads();
    m = fmaxf(fmaxf(r1[0], r1[1]), fmaxf(r1[2], r1[3]));

    float s = 0.f;
    #pragma unroll
    for (int j = 0; j < 8; ++j) { xv[j] = __expf(xv[j] - m); s += xv[j]; }
    #pragma unroll
    for (int off = 32; off; off >>= 1) s += __shfl_xor(s, off, 64);
    if ((t & 63) == 0) r2[t >> 6] = s;
    __syncthreads();
    s = r2[0] + r2[1] + r2[2] + r2[3];
    const float inv = 1.f / s;

    half8 o;
    #pragma unroll
    for (int j = 0; j < 8; ++j) o[j] = (f16)(xv[j] * inv);
    p[t] = o;
}

// ---------------------------------------------------------------------
extern "C" void kernel_launch(void* const* d_in, const int* in_sizes, int n_in,
                              void* d_out, int out_size, void* d_ws, size_t ws_size,
                              hipStream_t stream)
{
    const float* x  = (const float*)d_in[0];
    const float* Wq = (const float*)d_in[1];
    const float* bq = (const float*)d_in[2];
    const float* Wk = (const float*)d_in[3];
    const float* bk = (const float*)d_in[4];
    const float* Wv = (const float*)d_in[5];
    const float* bv = (const float*)d_in[6];
    float* out = (float*)d_out;

    char* ws = (char*)d_ws;
    const long MiB = 1024 * 1024;
    f16*   xh   = (f16*)  (ws + 0);          // 16 MiB [8192,1024]
    f16*   WT   = (f16*)  (ws + 16 * MiB);   //  6 MiB [3072,1024]
    float* bqkv = (float*)(ws + 22 * MiB);   // 12 KiB
    f16*   scores = (f16*) (ws + 0);         // 32 MiB [4][2048][2048]
    f16*   qk     = (f16*) (ws + 64 * MiB);  // 32 MiB [8192,2048]
    f16*   vT     = (f16*) (ws + 96 * MiB);  // 16 MiB [4][1024][2048]

    // 1) fused preprocessing
    preproc_k<<<8972, 256, 0, stream>>>(x, Wq, Wk, Wv, bq, bk, bv, xh, WT, bqkv);

    // 2) fused QKV projection: 128^2 3-buf (1536 blocks, integral packing)
    gemm_k<4, 4, true><<<dim3(64, 24, 1), 256, 49152, stream>>>(
        xh, WT, bqkv, nullptr, qk, vT,
        1024, 1024, 1024, 2048, 0, 0, 0);

    // 3) attention: scores via 256^2 8-phase (256 blocks = exact round)
    const long SS = (long)2048 * 2048;
    gemm8_k<1, false><<<dim3(8, 8, 4), 512, 131072, stream>>>(
        qk, qk + 1024, nullptr, nullptr, scores, nullptr,
        1024, 2048, 2048, 2048, SS, SS, SS);
    softmax_k<<<8192, 256, 0, stream>>>(scores);
    gemm_k<4, 0, false><<<dim3(16, 8, 4), 256, 49152, stream>>>(
        scores, vT, nullptr, out, nullptr, nullptr,
        2048, 2048, 2048, 1024, SS, (long)1024 * 2048, (long)2048 * 1024);
}